// Round 4
// baseline (472.337 us; speedup 1.0000x reference)
//
#include <hip/hip_runtime.h>

#define B_   16
#define C_   64
#define N_   2048
#define K_   20
#define T_   3
#define O_   64
#define EPS_ 1e-5f

#define NT    64          // points per block
#define ROWS  60          // T_*K_ rows per c-chunk
#define CT    (C_*T_)     // 192
#define RTOT  (CT*K_)     // 3840 total contraction rows

// ---------------------------------------------------------------------------
// Prep: fold BN scale into W2, transpose to [row][o] so lane=o is coalesced.
//   W2f[(c*60 + t*20 + k)*64 + o] = W2[o, c*3+t, k] * gamma[o]/sqrt(var[o]+eps)
//   bias2[o] = (b2[o]-mean[o])*inv[o] + beta[o]
// ---------------------------------------------------------------------------
__global__ void prep_kernel(const float* __restrict__ W2,
                            const float* __restrict__ b2,
                            const float* __restrict__ gamma,
                            const float* __restrict__ beta,
                            const float* __restrict__ run_mean,
                            const float* __restrict__ run_var,
                            float* __restrict__ W2f,
                            float* __restrict__ bias2) {
    int e = blockIdx.x * blockDim.x + threadIdx.x;
    const int total = RTOT * O_;
    if (e < total) {
        int row = e >> 6;        // /64
        int o   = e & 63;
        int c   = row / ROWS;
        int r2  = row % ROWS;
        int t   = r2 / K_;
        int k   = r2 % K_;
        float inv = gamma[o] * rsqrtf(run_var[o] + EPS_);
        W2f[e] = W2[(o * CT + (c * T_ + t)) * K_ + k] * inv;
    } else if (e < total + O_) {
        int o = e - total;
        float inv = gamma[o] * rsqrtf(run_var[o] + EPS_);
        bias2[o] = (b2[o] - run_mean[o]) * inv + beta[o];
    }
}

// ---------------------------------------------------------------------------
// Main: one block = (b, 64-point tile). 256 threads.
//   Phase A (once): stage idx, compute taylor[3][20][64pt] in LDS.
//   Loop c in 0..63:
//     stage W2f chunk [60][64] ; gather g=feat[b,c,idx] ; P[r2][pt]=g*tay
//     barrier
//     register-blocked 4x4: acc[pt4][o4] += P[r][pt] * W[r][o]
//     barrier
//   Epilogue: out = relu(acc + bias2)
// ---------------------------------------------------------------------------
__global__ __launch_bounds__(256) void spider_main(
    const float* __restrict__ feat,
    const int*   __restrict__ idx,
    const float* __restrict__ gpc,
    const float* __restrict__ W1,
    const float* __restrict__ b1,
    const float* __restrict__ W2f,
    const float* __restrict__ bias2,
    float* __restrict__ out)
{
    __shared__ __align__(16) int   s_idx[NT * K_];     // 5 KB
    __shared__ __align__(16) float s_tay[ROWS * NT];   // 15 KB  [t*20+k][pt]
    __shared__ __align__(16) float s_P  [ROWS * NT];   // 15 KB  [r2][pt]
    __shared__ __align__(16) float s_W  [ROWS * O_];   // 15 KB  [r2][o]

    const int tid = threadIdx.x;
    const int b   = blockIdx.y;
    const int n0  = blockIdx.x * NT;

    // ---- stage idx tile (contiguous region) + W1/b1 into s_W scratch ----
    const int* idxg = idx + ((size_t)b * N_ + n0) * K_;
    for (int j = tid; j < NT * K_; j += 256) s_idx[j] = idxg[j];
    if (tid < 57)      s_W[tid] = W1[tid];          // W1 is (3,19) row-major
    else if (tid < 60) s_W[tid] = b1[tid - 57];
    __syncthreads();

    // ---- taylor terms -> s_tay ----
    {
        const int pt  = tid & 63;
        const int kk0 = (tid >> 6) * 5;
        const float* pcb = gpc + ((size_t)b * 3 * N_ + (n0 + pt)) * K_;
        #pragma unroll
        for (int i = 0; i < 5; ++i) {
            int k = kk0 + i;
            float X = pcb[k];
            float Y = pcb[(size_t)N_ * K_ + k];
            float Z = pcb[(size_t)2 * N_ * K_ + k];
            float XX = X * X, YY = Y * Y, ZZ = Z * Z;
            float XY = X * Y, XZ = X * Z, YZ = Y * Z;
            float tm[19] = {X, Y, Z, XX, YY, ZZ,
                            XX * X, YY * Y, ZZ * Z,
                            XY, XZ, YZ,
                            X * XY, X * XZ, Y * YZ,
                            Y * XY, Z * XZ, Z * YZ, XY * Z};
            #pragma unroll
            for (int t = 0; t < 3; ++t) {
                float a = s_W[57 + t];
                #pragma unroll
                for (int j = 0; j < 19; ++j) a += s_W[t * 19 + j] * tm[j];
                s_tay[(t * K_ + k) * NT + pt] = a;
            }
        }
    }
    __syncthreads();

    float acc[4][4];   // [pt_j][o_i]
    #pragma unroll
    for (int j = 0; j < 4; ++j)
        #pragma unroll
        for (int i = 0; i < 4; ++i) acc[j][i] = 0.f;

    const int oc  = (tid & 15) * 4;     // o base for this thread
    const int pc  = (tid >> 4) * 4;     // pt base for this thread
    const int pt  = tid & 63;
    const int kk0 = (tid >> 6) * 5;
    const float* featb = feat + (size_t)b * C_ * N_;

    for (int c = 0; c < C_; ++c) {
        // stage W2f chunk for this c (coalesced)
        const float* wsrc = W2f + (size_t)c * (ROWS * O_);
        for (int j = tid; j < ROWS * O_; j += 256) s_W[j] = wsrc[j];

        // gather + form P
        const float* fr = featb + (size_t)c * N_;
        #pragma unroll
        for (int i = 0; i < 5; ++i) {
            int k = kk0 + i;
            float g = fr[s_idx[pt * K_ + k]];
            s_P[(0 * K_ + k) * NT + pt] = g * s_tay[(0 * K_ + k) * NT + pt];
            s_P[(1 * K_ + k) * NT + pt] = g * s_tay[(1 * K_ + k) * NT + pt];
            s_P[(2 * K_ + k) * NT + pt] = g * s_tay[(2 * K_ + k) * NT + pt];
        }
        __syncthreads();

        // register-blocked inner product
        #pragma unroll 6
        for (int r = 0; r < ROWS; ++r) {
            float4 w = *(const float4*)&s_W[r * O_ + oc];
            float4 p = *(const float4*)&s_P[r * NT + pc];
            acc[0][0] += p.x * w.x; acc[0][1] += p.x * w.y;
            acc[0][2] += p.x * w.z; acc[0][3] += p.x * w.w;
            acc[1][0] += p.y * w.x; acc[1][1] += p.y * w.y;
            acc[1][2] += p.y * w.z; acc[1][3] += p.y * w.w;
            acc[2][0] += p.z * w.x; acc[2][1] += p.z * w.y;
            acc[2][2] += p.z * w.z; acc[2][3] += p.z * w.w;
            acc[3][0] += p.w * w.x; acc[3][1] += p.w * w.y;
            acc[3][2] += p.w * w.z; acc[3][3] += p.w * w.w;
        }
        __syncthreads();
    }

    // ---- epilogue: bias + relu, write out[b, o, n] ----
    float bv[4];
    #pragma unroll
    for (int i = 0; i < 4; ++i) bv[i] = bias2[oc + i];
    #pragma unroll
    for (int j = 0; j < 4; ++j) {
        #pragma unroll
        for (int i = 0; i < 4; ++i) {
            float v = acc[j][i] + bv[i];
            out[((size_t)b * O_ + oc + i) * N_ + n0 + pc + j] = v > 0.f ? v : 0.f;
        }
    }
}

extern "C" void kernel_launch(void* const* d_in, const int* in_sizes, int n_in,
                              void* d_out, int out_size, void* d_ws, size_t ws_size,
                              hipStream_t stream) {
    const float* feat     = (const float*)d_in[0];
    const int*   idx      = (const int*)  d_in[1];
    const float* gpc      = (const float*)d_in[2];
    const float* W1       = (const float*)d_in[3];
    const float* b1       = (const float*)d_in[4];
    const float* W2       = (const float*)d_in[5];
    const float* b2       = (const float*)d_in[6];
    const float* gamma    = (const float*)d_in[7];
    const float* beta     = (const float*)d_in[8];
    const float* run_mean = (const float*)d_in[9];
    const float* run_var  = (const float*)d_in[10];
    float* out = (float*)d_out;

    float* W2f   = (float*)d_ws;               // 3840*64 floats
    float* bias2 = W2f + RTOT * O_;            // 64 floats

    const int prep_total = RTOT * O_ + O_;
    prep_kernel<<<(prep_total + 255) / 256, 256, 0, stream>>>(
        W2, b2, gamma, beta, run_mean, run_var, W2f, bias2);

    dim3 grid(N_ / NT, B_);
    spider_main<<<grid, 256, 0, stream>>>(
        feat, idx, gpc, W1, b1, W2f, bias2, out);
}

// Round 5
// 154.177 us; speedup vs baseline: 3.0636x; 3.0636x over previous
//
#include <hip/hip_runtime.h>

#define B_   16
#define C_   64
#define N_   2048
#define K_   20
#define O_   64
#define EPS_ 1e-5f

#define NT   32            // points per block
#define RP   64            // padded r per c-chunk (60 real + 4 zero)
#define CT   (C_*3)        // 192

typedef float  f32x4 __attribute__((ext_vector_type(4)));
typedef short  s16x8 __attribute__((ext_vector_type(8)));

__device__ __forceinline__ unsigned short f2bf(float x) {
    union { float f; unsigned int u; } v; v.f = x;
    unsigned int r = (v.u + 0x7fffu + ((v.u >> 16) & 1u)) >> 16;
    return (unsigned short)r;
}

// ---------------------------------------------------------------------------
// Prep: W2fb[c][o][r] bf16 with r = t*20+k (r<60), rows 60..63 zero-padded.
//   value = W2[o, c*3+t, k] * gamma[o]/sqrt(var[o]+eps)
// bias2[o] = (b2[o]-mean[o])*inv + beta[o]
// ---------------------------------------------------------------------------
__global__ void prep_kernel(const float* __restrict__ W2,
                            const float* __restrict__ b2,
                            const float* __restrict__ gamma,
                            const float* __restrict__ beta,
                            const float* __restrict__ run_mean,
                            const float* __restrict__ run_var,
                            unsigned short* __restrict__ W2fb,
                            float* __restrict__ bias2) {
    int e = blockIdx.x * blockDim.x + threadIdx.x;
    const int total = C_ * O_ * RP;      // 262144
    if (e < total) {
        int r = e & 63;
        int o = (e >> 6) & 63;
        int c = e >> 12;
        float v = 0.f;
        if (r < 60) {
            int t = r / K_, k = r % K_;
            float inv = gamma[o] * rsqrtf(run_var[o] + EPS_);
            v = W2[(o * CT + (c * 3 + t)) * K_ + k] * inv;
        }
        W2fb[e] = f2bf(v);
    } else if (e < total + O_) {
        int o = e - total;
        float inv = gamma[o] * rsqrtf(run_var[o] + EPS_);
        bias2[o] = (b2[o] - run_mean[o]) * inv + beta[o];
    }
}

// ---------------------------------------------------------------------------
// Main: block = (b, 32-pt tile), 128 threads (2 waves).
// GEMM: out[64o][32pt] = sum_r W[r][o] * P[r][pt], r=(c,t,k), K padded 64/c.
// A = W^T in LDS [o][64r] bf16 swizzled; B = P in LDS [pt][64r] bf16 swizzled.
// Swizzle: byte ^= ((row&7)<<4)  (applied on write AND read).
// mfma_f32_16x16x32_bf16: A row=l&15, k=(l>>4)*8+j; B col=l&15, same k;
//                         D row=(l>>4)*4+reg (=o), col=l&15 (=pt).
// ---------------------------------------------------------------------------
__global__ __launch_bounds__(128) void spider_mfma(
    const float* __restrict__ feat,
    const int*   __restrict__ idx,
    const float* __restrict__ gpc,
    const float* __restrict__ W1,
    const float* __restrict__ b1,
    const unsigned short* __restrict__ W2fb,
    const float* __restrict__ bias2,
    float* __restrict__ out)
{
    __shared__ __align__(16) float          s_tay[60 * NT];   // 7680 B
    __shared__ __align__(16) float          s_w1[60];
    __shared__ __align__(16) unsigned short s_W[O_ * RP];     // 8 KB [o][r] swz
    __shared__ __align__(16) unsigned short s_P[NT * RP];     // 4 KB [pt][r] swz

    const int tid = threadIdx.x;
    const int b   = blockIdx.y;
    const int n0  = blockIdx.x * NT;
    const int pt  = tid & 31;
    const int grp = tid >> 5;          // 0..3
    const int k0  = grp * 5;
    const int w   = tid >> 6;          // wave id 0..1
    const int l   = tid & 63;          // lane

    // stage W1/b1; zero the P pad rows (r=60..63 -> bytes 120..127, slot 7)
    if (tid < 57)      s_w1[tid] = W1[tid];
    else if (tid < 60) s_w1[tid] = b1[tid - 57];
    if (tid < NT) {
        int addr = tid * 128 + ((7 ^ (tid & 7)) << 4) + 8;
        *(unsigned long long*)((char*)s_P + addr) = 0ull;
    }
    __syncthreads();

    // ---- taylor terms -> s_tay[(t*20+k)*NT + pt] (fp32) ----
    {
        const float* pcb = gpc + ((size_t)b * 3 * N_ + (n0 + pt)) * K_;
        #pragma unroll
        for (int i = 0; i < 5; ++i) {
            int k = k0 + i;
            float X = pcb[k];
            float Y = pcb[(size_t)N_ * K_ + k];
            float Z = pcb[(size_t)2 * N_ * K_ + k];
            float XX = X * X, YY = Y * Y, ZZ = Z * Z;
            float XY = X * Y, XZ = X * Z, YZ = Y * Z;
            float tm[19] = {X, Y, Z, XX, YY, ZZ,
                            XX * X, YY * Y, ZZ * Z,
                            XY, XZ, YZ,
                            X * XY, X * XZ, Y * YZ,
                            Y * XY, Z * XZ, Z * YZ, XY * Z};
            #pragma unroll
            for (int t = 0; t < 3; ++t) {
                float a = s_w1[57 + t];
                #pragma unroll
                for (int j = 0; j < 19; ++j) a += s_w1[t * 19 + j] * tm[j];
                s_tay[(t * K_ + k) * NT + pt] = a;
            }
        }
    }

    // idx values held in registers for the whole c-loop
    int iv[5];
    {
        const int* ig = idx + ((size_t)b * N_ + n0 + pt) * K_ + k0;
        #pragma unroll
        for (int i = 0; i < 5; ++i) iv[i] = ig[i];
    }
    __syncthreads();

    f32x4 acc[2][2];
    #pragma unroll
    for (int mt = 0; mt < 2; ++mt)
        #pragma unroll
        for (int nt = 0; nt < 2; ++nt)
            acc[mt][nt] = (f32x4){0.f, 0.f, 0.f, 0.f};

    const float* featb = feat + (size_t)b * C_ * N_;

    for (int c = 0; c < C_; ++c) {
        // ---- stage W chunk: 512 x 16B slots, swizzled ds_write_b128 ----
        const s16x8* wg = (const s16x8*)(W2fb + (size_t)c * (O_ * RP));
        #pragma unroll
        for (int q = 0; q < 4; ++q) {
            int s  = tid * 4 + q;          // 0..511
            int o  = s >> 3, kb = s & 7;
            s16x8 v = wg[s];
            *(s16x8*)((char*)s_W + o * 128 + ((kb ^ (o & 7)) << 4)) = v;
        }
        // ---- gather (regs) + form P (bf16, swizzled b16 writes) ----
        const float* fr = featb + (size_t)c * N_;
        #pragma unroll
        for (int i = 0; i < 5; ++i) {
            int k = k0 + i;
            float g = fr[iv[i]];
            #pragma unroll
            for (int t = 0; t < 3; ++t) {
                float p = g * s_tay[(t * K_ + k) * NT + pt];
                int byte = (t * K_ + k) * 2;
                int addr = pt * 128 + (((byte >> 4) ^ (pt & 7)) << 4) + (byte & 15);
                *(unsigned short*)((char*)s_P + addr) = f2bf(p);
            }
        }
        __syncthreads();

        // ---- MFMA: wave w covers o in [w*32, w*32+32), all 32 pts ----
        #pragma unroll
        for (int ks = 0; ks < 2; ++ks) {
            int kb8 = ks * 4 + (l >> 4);
            int o0 = w * 32 + (l & 15);
            int o1 = o0 + 16;
            int p0 = (l & 15);
            int p1 = p0 + 16;
            s16x8 a0 = *(const s16x8*)((char*)s_W + o0 * 128 + ((kb8 ^ (o0 & 7)) << 4));
            s16x8 a1 = *(const s16x8*)((char*)s_W + o1 * 128 + ((kb8 ^ (o1 & 7)) << 4));
            s16x8 b0 = *(const s16x8*)((char*)s_P + p0 * 128 + ((kb8 ^ (p0 & 7)) << 4));
            s16x8 b1 = *(const s16x8*)((char*)s_P + p1 * 128 + ((kb8 ^ (p1 & 7)) << 4));
            acc[0][0] = __builtin_amdgcn_mfma_f32_16x16x32_bf16(a0, b0, acc[0][0], 0, 0, 0);
            acc[0][1] = __builtin_amdgcn_mfma_f32_16x16x32_bf16(a0, b1, acc[0][1], 0, 0, 0);
            acc[1][0] = __builtin_amdgcn_mfma_f32_16x16x32_bf16(a1, b0, acc[1][0], 0, 0, 0);
            acc[1][1] = __builtin_amdgcn_mfma_f32_16x16x32_bf16(a1, b1, acc[1][1], 0, 0, 0);
        }
        __syncthreads();
    }

    // ---- epilogue: bias + relu; D row=(l>>4)*4+reg (=o), col=l&15 (=pt) ----
    #pragma unroll
    for (int mt = 0; mt < 2; ++mt) {
        #pragma unroll
        for (int nt = 0; nt < 2; ++nt) {
            #pragma unroll
            for (int r = 0; r < 4; ++r) {
                int o = w * 32 + mt * 16 + (l >> 4) * 4 + r;
                int n = n0 + nt * 16 + (l & 15);
                float v = acc[mt][nt][r] + bias2[o];
                out[((size_t)b * O_ + o) * N_ + n] = fmaxf(v, 0.f);
            }
        }
    }
}

extern "C" void kernel_launch(void* const* d_in, const int* in_sizes, int n_in,
                              void* d_out, int out_size, void* d_ws, size_t ws_size,
                              hipStream_t stream) {
    const float* feat     = (const float*)d_in[0];
    const int*   idx      = (const int*)  d_in[1];
    const float* gpc      = (const float*)d_in[2];
    const float* W1       = (const float*)d_in[3];
    const float* b1       = (const float*)d_in[4];
    const float* W2       = (const float*)d_in[5];
    const float* b2       = (const float*)d_in[6];
    const float* gamma    = (const float*)d_in[7];
    const float* beta     = (const float*)d_in[8];
    const float* run_mean = (const float*)d_in[9];
    const float* run_var  = (const float*)d_in[10];
    float* out = (float*)d_out;

    unsigned short* W2fb = (unsigned short*)d_ws;                 // 512 KB
    float* bias2 = (float*)((char*)d_ws + (size_t)C_ * O_ * RP * 2);

    const int prep_total = C_ * O_ * RP + O_;
    prep_kernel<<<(prep_total + 255) / 256, 256, 0, stream>>>(
        W2, b2, gamma, beta, run_mean, run_var, W2fb, bias2);

    dim3 grid(N_ / NT, B_);
    spider_mfma<<<grid, 128, 0, stream>>>(
        feat, idx, gpc, W1, b1, W2fb, bias2, out);
}